// Round 10
// baseline (204.945 us; speedup 1.0000x reference)
//
#include <hip/hip_runtime.h>
#include <hip/hip_cooperative_groups.h>
#include <math.h>

namespace cg = cooperative_groups;

#define Bsz 8
#define Nn 1024
#define Ff 512
#define Hh 4
#define Dd 128

typedef float f32x4 __attribute__((ext_vector_type(4)));
typedef short bf16x8 __attribute__((ext_vector_type(8)));

__device__ inline uint f2b1(float a) {
    union { float f; uint u; } v; v.f = a;
    return (v.u + 0x7fffu + ((v.u >> 16) & 1u)) >> 16;   // RNE f32->bf16
}
__device__ inline uint f2b_pk(float a, float b) { return f2b1(a) | (f2b1(b) << 16); }

// hT2 layout: el = ((b*32 + (j>>5))*512 + hd)*32 + (j&31)
// Wc layout:  el = (((nc*64 + kblk)*8 + nt)*16 + n15)*8 + k7
// Single cooperative kernel: conv -> grid.sync -> gemm -> grid.sync -> attn.
// No kernel-boundary L2 invalidation: Xc and hT stay resident in XCD-local L2.

__global__ __launch_bounds__(512, 2) void fused_gat(const float* __restrict__ X,
                                                    const int*   __restrict__ mask,
                                                    const float* __restrict__ Wm,
                                                    const float* __restrict__ a_src,
                                                    const float* __restrict__ a_dst,
                                                    const float* __restrict__ gamma,
                                                    const float* __restrict__ beta,
                                                    float* __restrict__ out,
                                                    ushort* __restrict__ hT,
                                                    ushort* __restrict__ Xc,
                                                    ushort* __restrict__ Wc,
                                                    float* __restrict__ ei_g,
                                                    float* __restrict__ ej_g) {
    __shared__ float tile[8 * 520];    // conv W transpose (16.6 KB)
    __shared__ float s_ep[32 * 516];   // attn epilogue (66 KB)
    __shared__ float s_as[4][32];

    cg::grid_group grid = cg::this_grid();
    const int idx = blockIdx.x;        // 0..255
    const int tid = threadIdx.x;       // 0..511
    const int b = idx & 7;             // XCD-matched across all phases

    // ================= phase 0: conv (X + W -> fragment-major bf16) =================
    {
        // X part: every block converts 2 mtiles (XCD-matched: rows of batch b)
        const int s = idx >> 3;                    // 0..31
        const int half = tid >> 8, t = tid & 255;
        const int mtile = b * 64 + s * 2 + half;
        const int kblk = t >> 2, m15b = (t & 3) * 4;
        #pragma unroll
        for (int c = 0; c < 4; ++c) {
            int m15 = m15b + c;
            const float4* xp = (const float4*)(X + (size_t)(mtile * 16 + m15) * Ff + kblk * 8);
            float4 f0 = xp[0], f1 = xp[1];
            uint4 o = { f2b_pk(f0.x, f0.y), f2b_pk(f0.z, f0.w),
                        f2b_pk(f1.x, f1.y), f2b_pk(f1.z, f1.w) };
            *(uint4*)(Xc + (((size_t)(mtile * 64 + kblk) * 16 + m15) << 3)) = o;
        }
        // W part: blocks 0..63, one 8-k-row stripe each, LDS-transposed
        if (idx < 64) {
            const int kb = idx;
            const int kr = tid >> 6, col0 = (tid & 63) * 8;
            const float4* wp = (const float4*)(Wm + (size_t)(kb * 8 + kr) * Ff + col0);
            float4 a = wp[0], c = wp[1];
            *(float4*)(&tile[kr * 520 + col0]) = a;
            *(float4*)(&tile[kr * 520 + col0 + 4]) = c;
            __syncthreads();
            const int n = tid;                     // 0..511
            float v[8];
            #pragma unroll
            for (int u = 0; u < 8; ++u) v[u] = tile[u * 520 + n];
            uint4 o = { f2b_pk(v[0], v[1]), f2b_pk(v[2], v[3]),
                        f2b_pk(v[4], v[5]), f2b_pk(v[6], v[7]) };
            int nc = n >> 7, nt = (n >> 4) & 7, n15 = n & 15;
            *(uint4*)(Wc + ((size_t)(((nc * 64 + kb) * 8 + nt) * 16 + n15) << 3)) = o;
        }
    }
    grid.sync();

    // ================= phase 1: GEMM hT2 = (x@W)^T + exact e_i/e_j =================
    {
        const int w8 = tid >> 6;                   // 0..7
        const int lane = tid & 63, quad = lane >> 4, l16 = lane & 15;
        const int mi = (idx >> 3) & 15, ncp = idx >> 7;
        const int nc = ncp * 2 + (w8 >> 2), w = w8 & 3;
        const int mtile = (b * 16 + mi) * 4 + w;

        f32x4 z = {0.f, 0.f, 0.f, 0.f};
        f32x4 acc[8];
        #pragma unroll
        for (int nt = 0; nt < 8; ++nt) acc[nt] = z;

        const ushort* ap = Xc + ((size_t)mtile << 13) + quad * 128 + l16 * 8;
        const ushort* bp = Wc + ((size_t)nc << 16) + quad * 1024 + l16 * 8;

        bf16x8 ab[2];
        bf16x8 bb[2][8];
        ab[0] = *(const bf16x8*)(ap);
        ab[1] = *(const bf16x8*)(ap + 512);
        #pragma unroll
        for (int nt = 0; nt < 8; ++nt) {
            bb[0][nt] = *(const bf16x8*)(bp + nt * 128);
            bb[1][nt] = *(const bf16x8*)(bp + 4096 + nt * 128);
        }

        #pragma unroll 2
        for (int s = 0; s < 16; ++s) {
            const int c = s & 1;
            #pragma unroll
            for (int nt = 0; nt < 8; ++nt)
                acc[nt] = __builtin_amdgcn_mfma_f32_16x16x32_bf16(ab[c], bb[c][nt], acc[nt], 0, 0, 0);
            if (s + 2 < 16) {
                ab[c] = *(const bf16x8*)(ap + (s + 2) * 512);
                #pragma unroll
                for (int nt = 0; nt < 8; ++nt)
                    bb[c][nt] = *(const bf16x8*)(bp + (s + 2) * 4096 + nt * 128);
            }
        }

        const int nseq = (mi * 4 + w) * 16 + quad * 4;
        const int jb = nseq >> 5, js = nseq & 31;
        #pragma unroll
        for (int nt = 0; nt < 8; ++nt) {
            uint2 pv;
            pv.x = f2b_pk(acc[nt][0], acc[nt][1]);
            pv.y = f2b_pk(acc[nt][2], acc[nt][3]);
            int hd = nc * 128 + nt * 16 + l16;
            *(uint2*)(hT + ((size_t)(b * 32 + jb)) * 16384 + (size_t)hd * 32 + js) = pv;
        }

        {
            float as4[8], ad4[8];
            #pragma unroll
            for (int nt = 0; nt < 8; ++nt) {
                as4[nt] = a_src[nc * 128 + nt * 16 + l16];
                ad4[nt] = a_dst[nc * 128 + nt * 16 + l16];
            }
            #pragma unroll
            for (int rr = 0; rr < 4; ++rr) {
                float v1 = 0.f, v2 = 0.f;
                #pragma unroll
                for (int nt = 0; nt < 8; ++nt) {
                    v1 += acc[nt][rr] * as4[nt];
                    v2 += acc[nt][rr] * ad4[nt];
                }
                #pragma unroll
                for (int off = 1; off < 16; off <<= 1) {
                    v1 += __shfl_xor(v1, off);
                    v2 += __shfl_xor(v2, off);
                }
                if (l16 == 0) {
                    int n = nseq + rr;
                    ei_g[((b * 4 + nc) << 10) + n] = v1;
                    ej_g[((b * 4 + nc) << 10) + n] = v2;
                }
            }
        }
    }
    grid.sync();

    // ================= phase 2: attention + PV MFMA + residual + LayerNorm =================
    {
        const int i0 = (idx >> 3) * 32;
        const int w = tid >> 6, w4 = w & 3, jh = w >> 2;
        const int lane = tid & 63, quad = lane >> 4, l16 = lane & 15;

        const float* ejh = ej_g + ((b * 4 + w4) << 10);
        const int* mkb = mask + (b << 10);

        float maxej = -3.0e38f;
        #pragma unroll
        for (int k = 0; k < 16; ++k) maxej = fmaxf(maxej, ejh[lane + 64 * k]);
        #pragma unroll
        for (int off = 1; off < 64; off <<= 1) maxej = fmaxf(maxej, __shfl_xor(maxej, off));

        const float ei0 = ei_g[((b * 4 + w4) << 10) + i0 + l16];
        const float ei1 = ei_g[((b * 4 + w4) << 10) + i0 + 16 + l16];
        const int mi0 = mkb[i0 + l16];
        const int mi1 = mkb[i0 + 16 + l16];
        float m0, m1;
        { float t = ei0 + maxej; m0 = mi0 ? fmaxf(t, 0.2f * t) : -1e9f; }
        { float t = ei1 + maxej; m1 = mi1 ? fmaxf(t, 0.2f * t) : -1e9f; }

        f32x4 z = {0.f, 0.f, 0.f, 0.f};
        f32x4 acc[2][8], asum[2];
        #pragma unroll
        for (int it = 0; it < 2; ++it) { asum[it] = z;
            #pragma unroll
            for (int dt = 0; dt < 8; ++dt) acc[it][dt] = z; }
        bf16x8 ones;
        #pragma unroll
        for (int q = 0; q < 8; ++q) ones[q] = (short)0x3F80;

        const ushort* hTb = hT + ((size_t)(b * 32)) * 16384 + (size_t)(w4 * 128) * 32
                            + l16 * 32 + quad * 8;

        bf16x8 B[2][8];
        #pragma unroll
        for (int c = 0; c < 2; ++c) {
            const ushort* h0 = hTb + (size_t)(jh * 16 + c) * 16384;
            #pragma unroll
            for (int dt = 0; dt < 8; ++dt) B[c][dt] = *(const bf16x8*)(h0 + dt * 512);
        }

        #pragma unroll 2
        for (int r = 0; r < 16; ++r) {
            const int c = r & 1;
            const int jq = (jh * 16 + r) * 32 + quad * 8;
            float4 e0 = *(const float4*)(ejh + jq);
            float4 e1 = *(const float4*)(ejh + jq + 4);
            int4 q0 = *(const int4*)(mkb + jq);
            int4 q1 = *(const int4*)(mkb + jq + 4);
            float ev[8] = {e0.x, e0.y, e0.z, e0.w, e1.x, e1.y, e1.z, e1.w};
            int   mv[8] = {q0.x, q0.y, q0.z, q0.w, q1.x, q1.y, q1.z, q1.w};
            float wv0[8], wv1[8];
            #pragma unroll
            for (int u = 0; u < 8; ++u) {
                float t0 = ei0 + ev[u];
                float l0 = fmaxf(t0, 0.2f * t0);
                wv0[u] = __expf(((mi0 && mv[u]) ? l0 : -1e9f) - m0);
                float t1 = ei1 + ev[u];
                float l1 = fmaxf(t1, 0.2f * t1);
                wv1[u] = __expf(((mi1 && mv[u]) ? l1 : -1e9f) - m1);
            }
            union { uint4 u; bf16x8 v; } af0, af1;
            af0.u.x = f2b_pk(wv0[0], wv0[1]); af0.u.y = f2b_pk(wv0[2], wv0[3]);
            af0.u.z = f2b_pk(wv0[4], wv0[5]); af0.u.w = f2b_pk(wv0[6], wv0[7]);
            af1.u.x = f2b_pk(wv1[0], wv1[1]); af1.u.y = f2b_pk(wv1[2], wv1[3]);
            af1.u.z = f2b_pk(wv1[4], wv1[5]); af1.u.w = f2b_pk(wv1[6], wv1[7]);
            asum[0] = __builtin_amdgcn_mfma_f32_16x16x32_bf16(af0.v, ones, asum[0], 0, 0, 0);
            asum[1] = __builtin_amdgcn_mfma_f32_16x16x32_bf16(af1.v, ones, asum[1], 0, 0, 0);
            #pragma unroll
            for (int dt = 0; dt < 8; ++dt) {
                acc[0][dt] = __builtin_amdgcn_mfma_f32_16x16x32_bf16(af0.v, B[c][dt], acc[0][dt], 0, 0, 0);
                acc[1][dt] = __builtin_amdgcn_mfma_f32_16x16x32_bf16(af1.v, B[c][dt], acc[1][dt], 0, 0, 0);
            }
            if (r + 2 < 16) {
                const ushort* hn = hTb + (size_t)(jh * 16 + r + 2) * 16384;
                #pragma unroll
                for (int dt = 0; dt < 8; ++dt) B[c][dt] = *(const bf16x8*)(hn + dt * 512);
            }
        }

        if (jh == 1) {
            #pragma unroll
            for (int it = 0; it < 2; ++it)
                #pragma unroll
                for (int dt = 0; dt < 8; ++dt)
                    #pragma unroll
                    for (int rr = 0; rr < 4; ++rr)
                        s_ep[(it * 16 + quad * 4 + rr) * 516 + w4 * 128 + dt * 16 + l16] =
                            acc[it][dt][rr];
            if (l16 == 0) {
                #pragma unroll
                for (int it = 0; it < 2; ++it)
                    #pragma unroll
                    for (int rr = 0; rr < 4; ++rr)
                        s_as[w4][it * 16 + quad * 4 + rr] = asum[it][rr];
            }
        }
        __syncthreads();
        if (jh == 0) {
            float rs[2][4];
            #pragma unroll
            for (int it = 0; it < 2; ++it)
                #pragma unroll
                for (int rr = 0; rr < 4; ++rr)
                    rs[it][rr] = 1.f / (asum[it][rr] + s_as[w4][it * 16 + quad * 4 + rr]);
            #pragma unroll
            for (int it = 0; it < 2; ++it)
                #pragma unroll
                for (int dt = 0; dt < 8; ++dt)
                    #pragma unroll
                    for (int rr = 0; rr < 4; ++rr) {
                        int off = (it * 16 + quad * 4 + rr) * 516 + w4 * 128 + dt * 16 + l16;
                        s_ep[off] = (acc[it][dt][rr] + s_ep[off]) * rs[it][rr];
                    }
        }
        __syncthreads();

        #pragma unroll
        for (int q = 0; q < 4; ++q) {
            int ir = w * 4 + q;
            int ig = i0 + ir;
            float4 p0 = *(const float4*)(&s_ep[ir * 516 + lane * 8]);
            float4 p1 = *(const float4*)(&s_ep[ir * 516 + lane * 8 + 4]);
            const float* xp = X + (((size_t)((b << 10) + ig)) << 9) + lane * 8;
            float4 x0 = *(const float4*)(xp);
            float4 x1 = *(const float4*)(xp + 4);
            float v[8] = {p0.x + x0.x, p0.y + x0.y, p0.z + x0.z, p0.w + x0.w,
                          p1.x + x1.x, p1.y + x1.y, p1.z + x1.z, p1.w + x1.w};
            float s1 = 0.f, s2 = 0.f;
            #pragma unroll
            for (int u = 0; u < 8; ++u) { s1 += v[u]; s2 += v[u] * v[u]; }
            #pragma unroll
            for (int off = 1; off < 64; off <<= 1) { s1 += __shfl_xor(s1, off); s2 += __shfl_xor(s2, off); }
            float mean = s1 * (1.f / 512.f);
            float var  = s2 * (1.f / 512.f) - mean * mean;
            float rstd = rsqrtf(var + 1e-5f);
            int f0i = lane * 8;
            float4 g0 = *(const float4*)(gamma + f0i);
            float4 g1 = *(const float4*)(gamma + f0i + 4);
            float4 be0 = *(const float4*)(beta + f0i);
            float4 be1 = *(const float4*)(beta + f0i + 4);
            float* op = out + (((size_t)((b << 10) + ig)) << 9) + f0i;
            float4 o0, o1;
            o0.x = (v[0] - mean) * rstd * g0.x + be0.x;
            o0.y = (v[1] - mean) * rstd * g0.y + be0.y;
            o0.z = (v[2] - mean) * rstd * g0.z + be0.z;
            o0.w = (v[3] - mean) * rstd * g0.w + be0.w;
            o1.x = (v[4] - mean) * rstd * g1.x + be1.x;
            o1.y = (v[5] - mean) * rstd * g1.y + be1.y;
            o1.z = (v[6] - mean) * rstd * g1.z + be1.z;
            o1.w = (v[7] - mean) * rstd * g1.w + be1.w;
            *(float4*)op = o0;
            *(float4*)(op + 4) = o1;
        }
    }
}

extern "C" void kernel_launch(void* const* d_in, const int* in_sizes, int n_in,
                              void* d_out, int out_size, void* d_ws, size_t ws_size,
                              hipStream_t stream) {
    const float* x     = (const float*)d_in[0];
    const int*   mask  = (const int*)d_in[1];
    const float* W     = (const float*)d_in[2];
    const float* a_src = (const float*)d_in[3];
    const float* a_dst = (const float*)d_in[4];
    const float* gamma = (const float*)d_in[5];
    const float* beta  = (const float*)d_in[6];
    float* out = (float*)d_out;

    ushort* hT = (ushort*)d_ws;                            // 8 MB
    ushort* Xc = hT + (size_t)8 * 512 * 1024;              // 8 MB
    ushort* Wc = Xc + (size_t)8 * 1024 * 512;              // 0.5 MB
    float* ei = (float*)(Wc + (size_t)512 * 512);          // 128 KB
    float* ej = ei + 32768;

    void* args[] = { (void*)&x, (void*)&mask, (void*)&W, (void*)&a_src, (void*)&a_dst,
                     (void*)&gamma, (void*)&beta, (void*)&out, (void*)&hT, (void*)&Xc,
                     (void*)&Wc, (void*)&ei, (void*)&ej };
    hipLaunchCooperativeKernel((const void*)fused_gat, dim3(256), dim3(512),
                               args, 0, stream);
}

// Round 11
// 147.873 us; speedup vs baseline: 1.3860x; 1.3860x over previous
//
#include <hip/hip_runtime.h>
#include <math.h>

#define Bsz 8
#define Nn 1024
#define Ff 512
#define Hh 4
#define Dd 128

typedef float f32x4 __attribute__((ext_vector_type(4)));
typedef short bf16x8 __attribute__((ext_vector_type(8)));

__device__ inline uint f2b1(float a) {
    union { float f; uint u; } v; v.f = a;
    return (v.u + 0x7fffu + ((v.u >> 16) & 1u)) >> 16;   // RNE f32->bf16
}
__device__ inline uint f2b_pk(float a, float b) { return f2b1(a) | (f2b1(b) << 16); }

// hT2 layout: el = ((b*32 + (j>>5))*512 + hd)*32 + (j&31)
// Wc layout:  el = (((nc*64 + kblk)*8 + nt)*16 + n15)*8 + k7

// ============ Kernel 0: pre-swizzle X and W into fragment-major bf16 (R9 verbatim) ============
__global__ __launch_bounds__(256) void conv_xw(const float* __restrict__ X,
                                               const float* __restrict__ Wm,
                                               ushort* __restrict__ Xc,
                                               ushort* __restrict__ Wc) {
    __shared__ float tile[8 * 520];
    const int bi = blockIdx.x, tid = threadIdx.x;
    if (bi < 512) {
        const int mtile = (bi & 7) * 64 + (bi >> 3);
        const int kblk = tid >> 2, m15b = (tid & 3) * 4;
        #pragma unroll
        for (int c = 0; c < 4; ++c) {
            int m15 = m15b + c;
            const float4* xp = (const float4*)(X + (size_t)(mtile * 16 + m15) * Ff + kblk * 8);
            float4 f0 = xp[0], f1 = xp[1];
            uint4 o = { f2b_pk(f0.x, f0.y), f2b_pk(f0.z, f0.w),
                        f2b_pk(f1.x, f1.y), f2b_pk(f1.z, f1.w) };
            *(uint4*)(Xc + (((size_t)(mtile * 64 + kblk) * 16 + m15) << 3)) = o;
        }
    } else {
        const int kb = bi - 512;
        const int l = tid & 63, wv = tid >> 6;
        const int col0 = l * 8;
        #pragma unroll
        for (int rsel = 0; rsel < 2; ++rsel) {
            int kr = wv + rsel * 4;
            const float4* wp = (const float4*)(Wm + (size_t)(kb * 8 + kr) * Ff + col0);
            float4 a = wp[0], c = wp[1];
            *(float4*)(&tile[kr * 520 + col0]) = a;
            *(float4*)(&tile[kr * 520 + col0 + 4]) = c;
        }
        __syncthreads();
        #pragma unroll
        for (int rsel = 0; rsel < 2; ++rsel) {
            int n = tid + rsel * 256;
            float v[8];
            #pragma unroll
            for (int u = 0; u < 8; ++u) v[u] = tile[u * 520 + n];
            uint4 o = { f2b_pk(v[0], v[1]), f2b_pk(v[2], v[3]),
                        f2b_pk(v[4], v[5]), f2b_pk(v[6], v[7]) };
            int nc = n >> 7, nt = (n >> 4) & 7, n15 = n & 15;
            *(uint4*)(Wc + ((size_t)(((nc * 64 + kb) * 8 + nt) * 16 + n15) << 3)) = o;
        }
    }
}

// ============ Kernel 1: zero-LDS GEMM hT2 = (x@W)^T + exact e_i/e_j (R9 verbatim) ============
__global__ __launch_bounds__(256, 2) void gemm_xw(const ushort* __restrict__ Xc,
                                                  const ushort* __restrict__ Wc,
                                                  const float* __restrict__ a_src,
                                                  const float* __restrict__ a_dst,
                                                  ushort* __restrict__ hT,
                                                  float* __restrict__ ei,
                                                  float* __restrict__ ej) {
    const int idx = blockIdx.x;
    const int b = idx & 7, sub = idx >> 3;
    const int mi = sub & 15, nc = sub >> 4;
    const int tid = threadIdx.x;
    const int w = tid >> 6, lane = tid & 63, quad = lane >> 4, l16 = lane & 15;
    const int mtile = (b * 16 + mi) * 4 + w;

    f32x4 z = {0.f, 0.f, 0.f, 0.f};
    f32x4 acc[8];
    #pragma unroll
    for (int nt = 0; nt < 8; ++nt) acc[nt] = z;

    const ushort* ap = Xc + ((size_t)mtile << 13) + quad * 128 + l16 * 8;
    const ushort* bp = Wc + ((size_t)nc << 16) + quad * 1024 + l16 * 8;

    bf16x8 ab[2];
    bf16x8 bb[2][8];
    ab[0] = *(const bf16x8*)(ap);
    ab[1] = *(const bf16x8*)(ap + 512);
    #pragma unroll
    for (int nt = 0; nt < 8; ++nt) {
        bb[0][nt] = *(const bf16x8*)(bp + nt * 128);
        bb[1][nt] = *(const bf16x8*)(bp + 4096 + nt * 128);
    }

    #pragma unroll 2
    for (int s = 0; s < 16; ++s) {
        const int c = s & 1;
        #pragma unroll
        for (int nt = 0; nt < 8; ++nt)
            acc[nt] = __builtin_amdgcn_mfma_f32_16x16x32_bf16(ab[c], bb[c][nt], acc[nt], 0, 0, 0);
        if (s + 2 < 16) {
            ab[c] = *(const bf16x8*)(ap + (s + 2) * 512);
            #pragma unroll
            for (int nt = 0; nt < 8; ++nt)
                bb[c][nt] = *(const bf16x8*)(bp + (s + 2) * 4096 + nt * 128);
        }
    }

    const int nseq = (mi * 4 + w) * 16 + quad * 4;
    const int jb = nseq >> 5, js = nseq & 31;
    #pragma unroll
    for (int nt = 0; nt < 8; ++nt) {
        uint2 pv;
        pv.x = f2b_pk(acc[nt][0], acc[nt][1]);
        pv.y = f2b_pk(acc[nt][2], acc[nt][3]);
        int hd = nc * 128 + nt * 16 + l16;
        *(uint2*)(hT + ((size_t)(b * 32 + jb)) * 16384 + (size_t)hd * 32 + js) = pv;
    }

    {
        float as4[8], ad4[8];
        #pragma unroll
        for (int nt = 0; nt < 8; ++nt) {
            as4[nt] = a_src[nc * 128 + nt * 16 + l16];
            ad4[nt] = a_dst[nc * 128 + nt * 16 + l16];
        }
        #pragma unroll
        for (int rr = 0; rr < 4; ++rr) {
            float v1 = 0.f, v2 = 0.f;
            #pragma unroll
            for (int nt = 0; nt < 8; ++nt) {
                v1 += acc[nt][rr] * as4[nt];
                v2 += acc[nt][rr] * ad4[nt];
            }
            #pragma unroll
            for (int off = 1; off < 16; off <<= 1) {
                v1 += __shfl_xor(v1, off);
                v2 += __shfl_xor(v2, off);
            }
            if (l16 == 0) {
                int n = nseq + rr;
                ei[((b * 4 + nc) << 10) + n] = v1;
                ej[((b * 4 + nc) << 10) + n] = v2;
            }
        }
    }
}

// ============ Kernel 2: attention + PV MFMA + residual + LayerNorm ============
// Grid 512 x 512 thr -> 2 blocks/CU, 4 waves/SIMD. 16 i-rows/block.
// 8 waves = (head w&3) x (D-half w>>2): each wave owns 4 dt rows over ALL 1024 j.
// No cross-wave merge (complete asum per wave); exp recomputed per D-half pair.
__global__ __launch_bounds__(512, 4) void attn_pv(const ushort* __restrict__ hT,
                                                  const float* __restrict__ ei_g,
                                                  const float* __restrict__ ej_g,
                                                  const int* __restrict__ mask,
                                                  const float* __restrict__ X,
                                                  const float* __restrict__ gamma,
                                                  const float* __restrict__ beta,
                                                  float* __restrict__ out) {
    __shared__ float s_ep[16 * 516];   // 33 KB

    const int idx = blockIdx.x;
    const int b = idx & 7, i0 = (idx >> 3) * 16;
    const int tid = threadIdx.x;
    const int w = tid >> 6, w4 = w & 3, dh = w >> 2;
    const int lane = tid & 63, quad = lane >> 4, l16 = lane & 15;

    const float* ejh = ej_g + ((b * 4 + w4) << 10);
    const int* mkb = mask + (b << 10);

    // per-head max_j e_j (upper bound for exact softmax shift; leaky is monotone)
    float maxej = -3.0e38f;
    #pragma unroll
    for (int k = 0; k < 16; ++k) maxej = fmaxf(maxej, ejh[lane + 64 * k]);
    #pragma unroll
    for (int off = 1; off < 64; off <<= 1) maxej = fmaxf(maxej, __shfl_xor(maxej, off));

    const float ei_r = ei_g[((b * 4 + w4) << 10) + i0 + l16];
    const int mi_r = mkb[i0 + l16];
    float m_r;
    { float t = ei_r + maxej; m_r = mi_r ? fmaxf(t, 0.2f * t) : -1e9f; }

    f32x4 z = {0.f, 0.f, 0.f, 0.f};
    f32x4 acc[4], asum = z;
    #pragma unroll
    for (int dt = 0; dt < 4; ++dt) acc[dt] = z;
    bf16x8 ones;
    #pragma unroll
    for (int q = 0; q < 8; ++q) ones[q] = (short)0x3F80;   // bf16 1.0

    // base: rows hd = w4*128 + (dh*4+dt)*16 + l16; element (b*32+r)*16384 + hd*32 + quad*8
    const ushort* hTb = hT + ((size_t)(b * 32)) * 16384 + (size_t)(w4 * 128) * 32
                        + dh * 2048 + l16 * 32 + quad * 8;

    // prefetch steps 0,1 (depth 2)
    bf16x8 B[2][4];
    #pragma unroll
    for (int c = 0; c < 2; ++c) {
        const ushort* h0 = hTb + (size_t)c * 16384;
        #pragma unroll
        for (int dt = 0; dt < 4; ++dt) B[c][dt] = *(const bf16x8*)(h0 + dt * 512);
    }

    #pragma unroll 2
    for (int r = 0; r < 32; ++r) {
        const int c = r & 1;
        const int jq = r * 32 + quad * 8;
        float4 e0 = *(const float4*)(ejh + jq);
        float4 e1 = *(const float4*)(ejh + jq + 4);
        int4 q0 = *(const int4*)(mkb + jq);
        int4 q1 = *(const int4*)(mkb + jq + 4);
        float ev[8] = {e0.x, e0.y, e0.z, e0.w, e1.x, e1.y, e1.z, e1.w};
        int   mv[8] = {q0.x, q0.y, q0.z, q0.w, q1.x, q1.y, q1.z, q1.w};
        float wv[8];
        #pragma unroll
        for (int u = 0; u < 8; ++u) {
            float t = ei_r + ev[u];
            float l = fmaxf(t, 0.2f * t);               // leaky_relu 0.2
            float lg = (mi_r && mv[u]) ? l : -1e9f;
            wv[u] = __expf(lg - m_r);                   // un-normalized weight
        }
        union { uint4 u; bf16x8 v; } af;
        af.u.x = f2b_pk(wv[0], wv[1]);
        af.u.y = f2b_pk(wv[2], wv[3]);
        af.u.z = f2b_pk(wv[4], wv[5]);
        af.u.w = f2b_pk(wv[6], wv[7]);
        asum = __builtin_amdgcn_mfma_f32_16x16x32_bf16(af.v, ones, asum, 0, 0, 0);
        #pragma unroll
        for (int dt = 0; dt < 4; ++dt)
            acc[dt] = __builtin_amdgcn_mfma_f32_16x16x32_bf16(af.v, B[c][dt], acc[dt], 0, 0, 0);
        if (r + 2 < 32) {   // reload slot c for step r+2
            const ushort* hn = hTb + (size_t)(r + 2) * 16384;
            #pragma unroll
            for (int dt = 0; dt < 4; ++dt) B[c][dt] = *(const bf16x8*)(hn + dt * 512);
        }
    }

    // normalize (complete asum per wave) + transpose via LDS
    float rsv[4];
    #pragma unroll
    for (int rr = 0; rr < 4; ++rr) rsv[rr] = 1.f / asum[rr];
    #pragma unroll
    for (int dt = 0; dt < 4; ++dt)
        #pragma unroll
        for (int rr = 0; rr < 4; ++rr)
            s_ep[(quad * 4 + rr) * 516 + w4 * 128 + (dh * 4 + dt) * 16 + l16] =
                acc[dt][rr] * rsv[rr];
    __syncthreads();

    // residual + LayerNorm: 8 waves x 2 rows
    #pragma unroll
    for (int q = 0; q < 2; ++q) {
        int ir = w * 2 + q;
        int ig = i0 + ir;
        float4 p0 = *(const float4*)(&s_ep[ir * 516 + lane * 8]);
        float4 p1 = *(const float4*)(&s_ep[ir * 516 + lane * 8 + 4]);
        const float* xp = X + (((size_t)((b << 10) + ig)) << 9) + lane * 8;
        float4 x0 = *(const float4*)(xp);
        float4 x1 = *(const float4*)(xp + 4);
        float v[8] = {p0.x + x0.x, p0.y + x0.y, p0.z + x0.z, p0.w + x0.w,
                      p1.x + x1.x, p1.y + x1.y, p1.z + x1.z, p1.w + x1.w};
        float s1 = 0.f, s2 = 0.f;
        #pragma unroll
        for (int u = 0; u < 8; ++u) { s1 += v[u]; s2 += v[u] * v[u]; }
        #pragma unroll
        for (int off = 1; off < 64; off <<= 1) { s1 += __shfl_xor(s1, off); s2 += __shfl_xor(s2, off); }
        float mean = s1 * (1.f / 512.f);
        float var  = s2 * (1.f / 512.f) - mean * mean;
        float rstd = rsqrtf(var + 1e-5f);
        int f0i = lane * 8;
        float4 g0 = *(const float4*)(gamma + f0i);
        float4 g1 = *(const float4*)(gamma + f0i + 4);
        float4 be0 = *(const float4*)(beta + f0i);
        float4 be1 = *(const float4*)(beta + f0i + 4);
        float* op = out + (((size_t)((b << 10) + ig)) << 9) + f0i;
        float4 o0, o1;
        o0.x = (v[0] - mean) * rstd * g0.x + be0.x;
        o0.y = (v[1] - mean) * rstd * g0.y + be0.y;
        o0.z = (v[2] - mean) * rstd * g0.z + be0.z;
        o0.w = (v[3] - mean) * rstd * g0.w + be0.w;
        o1.x = (v[4] - mean) * rstd * g1.x + be1.x;
        o1.y = (v[5] - mean) * rstd * g1.y + be1.y;
        o1.z = (v[6] - mean) * rstd * g1.z + be1.z;
        o1.w = (v[7] - mean) * rstd * g1.w + be1.w;
        *(float4*)op = o0;
        *(float4*)(op + 4) = o1;
    }
}

extern "C" void kernel_launch(void* const* d_in, const int* in_sizes, int n_in,
                              void* d_out, int out_size, void* d_ws, size_t ws_size,
                              hipStream_t stream) {
    const float* x     = (const float*)d_in[0];
    const int*   mask  = (const int*)d_in[1];
    const float* W     = (const float*)d_in[2];
    const float* a_src = (const float*)d_in[3];
    const float* a_dst = (const float*)d_in[4];
    const float* gamma = (const float*)d_in[5];
    const float* beta  = (const float*)d_in[6];
    float* out = (float*)d_out;

    ushort* hT = (ushort*)d_ws;                            // 8 MB
    ushort* Xc = hT + (size_t)8 * 512 * 1024;              // 8 MB
    ushort* Wc = Xc + (size_t)8 * 1024 * 512;              // 0.5 MB
    float* ei = (float*)(Wc + (size_t)512 * 512);          // 128 KB
    float* ej = ei + 32768;

    conv_xw<<<dim3(576), 256, 0, stream>>>(x, W, Xc, Wc);
    gemm_xw<<<dim3(512), 256, 0, stream>>>(Xc, Wc, a_src, a_dst, hT, ei, ej);
    attn_pv<<<dim3(512), 512, 0, stream>>>(hT, ei, ej, mask, x, gamma, beta, out);
}

// Round 12
// 127.533 us; speedup vs baseline: 1.6070x; 1.1595x over previous
//
#include <hip/hip_runtime.h>
#include <math.h>

#define Bsz 8
#define Nn 1024
#define Ff 512
#define Hh 4
#define Dd 128
#define LOG2E 1.44269504088896340736f

typedef float f32x4 __attribute__((ext_vector_type(4)));
typedef short bf16x8 __attribute__((ext_vector_type(8)));

__device__ inline uint f2b1(float a) {
    union { float f; uint u; } v; v.f = a;
    return (v.u + 0x7fffu + ((v.u >> 16) & 1u)) >> 16;   // RNE f32->bf16
}
__device__ inline uint f2b_pk(float a, float b) { return f2b1(a) | (f2b1(b) << 16); }

// hT2 layout: el = ((b*32 + (j>>5))*512 + hd)*32 + (j&31)
// Wc layout:  el = (((nc*64 + kblk)*8 + nt)*16 + n15)*8 + k7
// ei/ej are stored PRE-SCALED by log2(e); ej additionally has the j-mask folded in
// (ej_m = mask_j ? ej*log2e : -1e9) so attn's r-loop needs no mask loads and uses
// bare exp2 (leaky_relu commutes with positive scaling; softmax is shift-invariant).

// ============ Kernel 0: pre-swizzle X and W into fragment-major bf16 (R9 verbatim) ============
__global__ __launch_bounds__(256) void conv_xw(const float* __restrict__ X,
                                               const float* __restrict__ Wm,
                                               ushort* __restrict__ Xc,
                                               ushort* __restrict__ Wc) {
    __shared__ float tile[8 * 520];
    const int bi = blockIdx.x, tid = threadIdx.x;
    if (bi < 512) {
        const int mtile = (bi & 7) * 64 + (bi >> 3);
        const int kblk = tid >> 2, m15b = (tid & 3) * 4;
        #pragma unroll
        for (int c = 0; c < 4; ++c) {
            int m15 = m15b + c;
            const float4* xp = (const float4*)(X + (size_t)(mtile * 16 + m15) * Ff + kblk * 8);
            float4 f0 = xp[0], f1 = xp[1];
            uint4 o = { f2b_pk(f0.x, f0.y), f2b_pk(f0.z, f0.w),
                        f2b_pk(f1.x, f1.y), f2b_pk(f1.z, f1.w) };
            *(uint4*)(Xc + (((size_t)(mtile * 64 + kblk) * 16 + m15) << 3)) = o;
        }
    } else {
        const int kb = bi - 512;
        const int l = tid & 63, wv = tid >> 6;
        const int col0 = l * 8;
        #pragma unroll
        for (int rsel = 0; rsel < 2; ++rsel) {
            int kr = wv + rsel * 4;
            const float4* wp = (const float4*)(Wm + (size_t)(kb * 8 + kr) * Ff + col0);
            float4 a = wp[0], c = wp[1];
            *(float4*)(&tile[kr * 520 + col0]) = a;
            *(float4*)(&tile[kr * 520 + col0 + 4]) = c;
        }
        __syncthreads();
        #pragma unroll
        for (int rsel = 0; rsel < 2; ++rsel) {
            int n = tid + rsel * 256;
            float v[8];
            #pragma unroll
            for (int u = 0; u < 8; ++u) v[u] = tile[u * 520 + n];
            uint4 o = { f2b_pk(v[0], v[1]), f2b_pk(v[2], v[3]),
                        f2b_pk(v[4], v[5]), f2b_pk(v[6], v[7]) };
            int nc = n >> 7, nt = (n >> 4) & 7, n15 = n & 15;
            *(uint4*)(Wc + ((size_t)(((nc * 64 + kb) * 8 + nt) * 16 + n15) << 3)) = o;
        }
    }
}

// ============ Kernel 1: zero-LDS GEMM hT2 = (x@W)^T + exact e_i/e_j (scaled/masked) ============
__global__ __launch_bounds__(256, 2) void gemm_xw(const ushort* __restrict__ Xc,
                                                  const ushort* __restrict__ Wc,
                                                  const float* __restrict__ a_src,
                                                  const float* __restrict__ a_dst,
                                                  const int* __restrict__ mask,
                                                  ushort* __restrict__ hT,
                                                  float* __restrict__ ei,
                                                  float* __restrict__ ej) {
    const int idx = blockIdx.x;
    const int b = idx & 7, sub = idx >> 3;
    const int mi = sub & 15, nc = sub >> 4;
    const int tid = threadIdx.x;
    const int w = tid >> 6, lane = tid & 63, quad = lane >> 4, l16 = lane & 15;
    const int mtile = (b * 16 + mi) * 4 + w;

    f32x4 z = {0.f, 0.f, 0.f, 0.f};
    f32x4 acc[8];
    #pragma unroll
    for (int nt = 0; nt < 8; ++nt) acc[nt] = z;

    const ushort* ap = Xc + ((size_t)mtile << 13) + quad * 128 + l16 * 8;
    const ushort* bp = Wc + ((size_t)nc << 16) + quad * 1024 + l16 * 8;

    bf16x8 ab[2];
    bf16x8 bb[2][8];
    ab[0] = *(const bf16x8*)(ap);
    ab[1] = *(const bf16x8*)(ap + 512);
    #pragma unroll
    for (int nt = 0; nt < 8; ++nt) {
        bb[0][nt] = *(const bf16x8*)(bp + nt * 128);
        bb[1][nt] = *(const bf16x8*)(bp + 4096 + nt * 128);
    }

    #pragma unroll 2
    for (int s = 0; s < 16; ++s) {
        const int c = s & 1;
        #pragma unroll
        for (int nt = 0; nt < 8; ++nt)
            acc[nt] = __builtin_amdgcn_mfma_f32_16x16x32_bf16(ab[c], bb[c][nt], acc[nt], 0, 0, 0);
        if (s + 2 < 16) {
            ab[c] = *(const bf16x8*)(ap + (s + 2) * 512);
            #pragma unroll
            for (int nt = 0; nt < 8; ++nt)
                bb[c][nt] = *(const bf16x8*)(bp + (s + 2) * 4096 + nt * 128);
        }
    }

    const int nseq = (mi * 4 + w) * 16 + quad * 4;
    const int jb = nseq >> 5, js = nseq & 31;
    #pragma unroll
    for (int nt = 0; nt < 8; ++nt) {
        uint2 pv;
        pv.x = f2b_pk(acc[nt][0], acc[nt][1]);
        pv.y = f2b_pk(acc[nt][2], acc[nt][3]);
        int hd = nc * 128 + nt * 16 + l16;
        *(uint2*)(hT + ((size_t)(b * 32 + jb)) * 16384 + (size_t)hd * 32 + js) = pv;
    }

    {
        float as4[8], ad4[8];
        #pragma unroll
        for (int nt = 0; nt < 8; ++nt) {
            as4[nt] = a_src[nc * 128 + nt * 16 + l16];
            ad4[nt] = a_dst[nc * 128 + nt * 16 + l16];
        }
        #pragma unroll
        for (int rr = 0; rr < 4; ++rr) {
            float v1 = 0.f, v2 = 0.f;
            #pragma unroll
            for (int nt = 0; nt < 8; ++nt) {
                v1 += acc[nt][rr] * as4[nt];
                v2 += acc[nt][rr] * ad4[nt];
            }
            #pragma unroll
            for (int off = 1; off < 16; off <<= 1) {
                v1 += __shfl_xor(v1, off);
                v2 += __shfl_xor(v2, off);
            }
            if (l16 == 0) {
                int n = nseq + rr;
                ei[((b * 4 + nc) << 10) + n] = v1 * LOG2E;
                ej[((b * 4 + nc) << 10) + n] = mask[(b << 10) + n] ? v2 * LOG2E : -1e9f;
            }
        }
    }
}

// ============ Kernel 2: attention + PV MFMA + residual + LayerNorm ============
// R9 structure: grid 256, 512 thr = 8 waves (head w&3, j-half w>>2), 32 i-rows/block,
// depth-2 B prefetch, jh-merge via LDS. Weight pipeline: no mask loads, bare exp2.
__global__ __launch_bounds__(512, 2) void attn_pv(const ushort* __restrict__ hT,
                                                  const float* __restrict__ ei_g,
                                                  const float* __restrict__ ej_g,
                                                  const int* __restrict__ mask,
                                                  const float* __restrict__ X,
                                                  const float* __restrict__ gamma,
                                                  const float* __restrict__ beta,
                                                  float* __restrict__ out) {
    __shared__ float s_ep[32 * 516];
    __shared__ float s_as[4][32];

    const int idx = blockIdx.x;
    const int b = idx & 7, i0 = (idx >> 3) * 32;
    const int tid = threadIdx.x;
    const int w = tid >> 6, w4 = w & 3, jh = w >> 2;
    const int lane = tid & 63, quad = lane >> 4, l16 = lane & 15;

    const float* ejh = ej_g + ((b * 4 + w4) << 10);
    const int* mkb = mask + (b << 10);

    // masked max_j ej (valid shift: >= every unmasked logit's ej term; exact softmax)
    float maxej = -3.0e38f;
    #pragma unroll
    for (int k = 0; k < 16; ++k) maxej = fmaxf(maxej, ejh[lane + 64 * k]);
    #pragma unroll
    for (int off = 1; off < 64; off <<= 1) maxej = fmaxf(maxej, __shfl_xor(maxej, off));

    const float ei0 = ei_g[((b * 4 + w4) << 10) + i0 + l16];
    const float ei1 = ei_g[((b * 4 + w4) << 10) + i0 + 16 + l16];
    const int mi0 = mkb[i0 + l16];
    const int mi1 = mkb[i0 + 16 + l16];
    float m0, m1;
    { float t = ei0 + maxej; m0 = mi0 ? fmaxf(t, 0.2f * t) : -1e9f; }
    { float t = ei1 + maxej; m1 = mi1 ? fmaxf(t, 0.2f * t) : -1e9f; }

    f32x4 z = {0.f, 0.f, 0.f, 0.f};
    f32x4 acc[2][8], asum[2];
    #pragma unroll
    for (int it = 0; it < 2; ++it) { asum[it] = z;
        #pragma unroll
        for (int dt = 0; dt < 8; ++dt) acc[it][dt] = z; }
    bf16x8 ones;
    #pragma unroll
    for (int q = 0; q < 8; ++q) ones[q] = (short)0x3F80;

    const ushort* hTb = hT + ((size_t)(b * 32)) * 16384 + (size_t)(w4 * 128) * 32
                        + l16 * 32 + quad * 8;

    bf16x8 B[2][8];
    #pragma unroll
    for (int c = 0; c < 2; ++c) {
        const ushort* h0 = hTb + (size_t)(jh * 16 + c) * 16384;
        #pragma unroll
        for (int dt = 0; dt < 8; ++dt) B[c][dt] = *(const bf16x8*)(h0 + dt * 512);
    }

    #pragma unroll 2
    for (int r = 0; r < 16; ++r) {
        const int c = r & 1;
        const int jq = (jh * 16 + r) * 32 + quad * 8;
        float4 e0 = *(const float4*)(ejh + jq);
        float4 e1 = *(const float4*)(ejh + jq + 4);
        float ev[8] = {e0.x, e0.y, e0.z, e0.w, e1.x, e1.y, e1.z, e1.w};
        float wv0[8], wv1[8];
        #pragma unroll
        for (int u = 0; u < 8; ++u) {
            float t0 = ei0 + ev[u];
            float l0 = fmaxf(t0, 0.2f * t0);
            wv0[u] = mi0 ? exp2f(l0 - m0) : 1.0f;       // masked j -> underflow to 0
            float t1 = ei1 + ev[u];
            float l1 = fmaxf(t1, 0.2f * t1);
            wv1[u] = mi1 ? exp2f(l1 - m1) : 1.0f;
        }
        union { uint4 u; bf16x8 v; } af0, af1;
        af0.u.x = f2b_pk(wv0[0], wv0[1]); af0.u.y = f2b_pk(wv0[2], wv0[3]);
        af0.u.z = f2b_pk(wv0[4], wv0[5]); af0.u.w = f2b_pk(wv0[6], wv0[7]);
        af1.u.x = f2b_pk(wv1[0], wv1[1]); af1.u.y = f2b_pk(wv1[2], wv1[3]);
        af1.u.z = f2b_pk(wv1[4], wv1[5]); af1.u.w = f2b_pk(wv1[6], wv1[7]);
        asum[0] = __builtin_amdgcn_mfma_f32_16x16x32_bf16(af0.v, ones, asum[0], 0, 0, 0);
        asum[1] = __builtin_amdgcn_mfma_f32_16x16x32_bf16(af1.v, ones, asum[1], 0, 0, 0);
        #pragma unroll
        for (int dt = 0; dt < 8; ++dt) {
            acc[0][dt] = __builtin_amdgcn_mfma_f32_16x16x32_bf16(af0.v, B[c][dt], acc[0][dt], 0, 0, 0);
            acc[1][dt] = __builtin_amdgcn_mfma_f32_16x16x32_bf16(af1.v, B[c][dt], acc[1][dt], 0, 0, 0);
        }
        if (r + 2 < 16) {
            const ushort* hn = hTb + (size_t)(jh * 16 + r + 2) * 16384;
            #pragma unroll
            for (int dt = 0; dt < 8; ++dt) B[c][dt] = *(const bf16x8*)(hn + dt * 512);
        }
    }

    if (jh == 1) {
        #pragma unroll
        for (int it = 0; it < 2; ++it)
            #pragma unroll
            for (int dt = 0; dt < 8; ++dt)
                #pragma unroll
                for (int rr = 0; rr < 4; ++rr)
                    s_ep[(it * 16 + quad * 4 + rr) * 516 + w4 * 128 + dt * 16 + l16] =
                        acc[it][dt][rr];
        if (l16 == 0) {
            #pragma unroll
            for (int it = 0; it < 2; ++it)
                #pragma unroll
                for (int rr = 0; rr < 4; ++rr)
                    s_as[w4][it * 16 + quad * 4 + rr] = asum[it][rr];
        }
    }
    __syncthreads();
    if (jh == 0) {
        float rs[2][4];
        #pragma unroll
        for (int it = 0; it < 2; ++it)
            #pragma unroll
            for (int rr = 0; rr < 4; ++rr)
                rs[it][rr] = 1.f / (asum[it][rr] + s_as[w4][it * 16 + quad * 4 + rr]);
        #pragma unroll
        for (int it = 0; it < 2; ++it)
            #pragma unroll
            for (int dt = 0; dt < 8; ++dt)
                #pragma unroll
                for (int rr = 0; rr < 4; ++rr) {
                    int off = (it * 16 + quad * 4 + rr) * 516 + w4 * 128 + dt * 16 + l16;
                    s_ep[off] = (acc[it][dt][rr] + s_ep[off]) * rs[it][rr];
                }
    }
    __syncthreads();

    #pragma unroll
    for (int q = 0; q < 4; ++q) {
        int ir = w * 4 + q;
        int ig = i0 + ir;
        float4 p0 = *(const float4*)(&s_ep[ir * 516 + lane * 8]);
        float4 p1 = *(const float4*)(&s_ep[ir * 516 + lane * 8 + 4]);
        const float* xp = X + (((size_t)((b << 10) + ig)) << 9) + lane * 8;
        float4 x0 = *(const float4*)(xp);
        float4 x1 = *(const float4*)(xp + 4);
        float v[8] = {p0.x + x0.x, p0.y + x0.y, p0.z + x0.z, p0.w + x0.w,
                      p1.x + x1.x, p1.y + x1.y, p1.z + x1.z, p1.w + x1.w};
        float s1 = 0.f, s2 = 0.f;
        #pragma unroll
        for (int u = 0; u < 8; ++u) { s1 += v[u]; s2 += v[u] * v[u]; }
        #pragma unroll
        for (int off = 1; off < 64; off <<= 1) { s1 += __shfl_xor(s1, off); s2 += __shfl_xor(s2, off); }
        float mean = s1 * (1.f / 512.f);
        float var  = s2 * (1.f / 512.f) - mean * mean;
        float rstd = rsqrtf(var + 1e-5f);
        int f0i = lane * 8;
        float4 g0 = *(const float4*)(gamma + f0i);
        float4 g1 = *(const float4*)(gamma + f0i + 4);
        float4 be0 = *(const float4*)(beta + f0i);
        float4 be1 = *(const float4*)(beta + f0i + 4);
        float* op = out + (((size_t)((b << 10) + ig)) << 9) + f0i;
        float4 o0, o1;
        o0.x = (v[0] - mean) * rstd * g0.x + be0.x;
        o0.y = (v[1] - mean) * rstd * g0.y + be0.y;
        o0.z = (v[2] - mean) * rstd * g0.z + be0.z;
        o0.w = (v[3] - mean) * rstd * g0.w + be0.w;
        o1.x = (v[4] - mean) * rstd * g1.x + be1.x;
        o1.y = (v[5] - mean) * rstd * g1.y + be1.y;
        o1.z = (v[6] - mean) * rstd * g1.z + be1.z;
        o1.w = (v[7] - mean) * rstd * g1.w + be1.w;
        *(float4*)op = o0;
        *(float4*)(op + 4) = o1;
    }
}

extern "C" void kernel_launch(void* const* d_in, const int* in_sizes, int n_in,
                              void* d_out, int out_size, void* d_ws, size_t ws_size,
                              hipStream_t stream) {
    const float* x     = (const float*)d_in[0];
    const int*   mask  = (const int*)d_in[1];
    const float* W     = (const float*)d_in[2];
    const float* a_src = (const float*)d_in[3];
    const float* a_dst = (const float*)d_in[4];
    const float* gamma = (const float*)d_in[5];
    const float* beta  = (const float*)d_in[6];
    float* out = (float*)d_out;

    ushort* hT = (ushort*)d_ws;                            // 8 MB
    ushort* Xc = hT + (size_t)8 * 512 * 1024;              // 8 MB
    ushort* Wc = Xc + (size_t)8 * 1024 * 512;              // 0.5 MB
    float* ei = (float*)(Wc + (size_t)512 * 512);          // 128 KB
    float* ej = ei + 32768;

    conv_xw<<<dim3(576), 256, 0, stream>>>(x, W, Xc, Wc);
    gemm_xw<<<dim3(512), 256, 0, stream>>>(Xc, Wc, a_src, a_dst, mask, hT, ei, ej);
    attn_pv<<<dim3(256), 512, 0, stream>>>(hT, ei, ej, mask, x, gamma, beta, out);
}